// Round 7
// baseline (9072.652 us; speedup 1.0000x reference)
//
#include <hip/hip_runtime.h>

#define VOCAB 32000
#define EMBED 1024
#define HID   1024
#define BATCH 64
#define SEQ   512
#define R4    4096   // 4*HID gate rows (i,f,g,o)
#define NBLK  256    // legacy flag array size (fallback path)
#define PBLK  64     // phase-B grid size
#define UPB   16     // units per phase-B block
#define NREC  32768  // tagged records per h buffer (64 b x 512 pairs)
#define TAGB  0x5AD00000u

typedef float floatx4 __attribute__((ext_vector_type(4)));
typedef unsigned int uintx2 __attribute__((ext_vector_type(2)));
typedef short bf16x8  __attribute__((ext_vector_type(8)));   // 8 bf16 = 4 VGPRs
typedef unsigned long long u64;

// fp32 -> bf16 round-to-nearest-even
static __device__ __forceinline__ unsigned short f2bf(float x) {
    unsigned int u = __float_as_uint(x);
    u = (u + 0x7FFFu + ((u >> 16) & 1u)) >> 16;
    return (unsigned short)u;
}

// load 8 contiguous fp32, convert to bf16x8 fragment
static __device__ __forceinline__ bf16x8 cvt8(const float* p) {
    float4 a = ((const float4*)p)[0];
    float4 b = ((const float4*)p)[1];
    bf16x8 r;
    r[0] = (short)f2bf(a.x); r[1] = (short)f2bf(a.y);
    r[2] = (short)f2bf(a.z); r[3] = (short)f2bf(a.w);
    r[4] = (short)f2bf(b.x); r[5] = (short)f2bf(b.y);
    r[6] = (short)f2bf(b.z); r[7] = (short)f2bf(b.w);
    return r;
}

// ---------------------------------------------------------------------------
// Phase A: gx[s][r][b] = emb[seq[b][s]] . W_ih[r] + b_ih[r] + b_hh[r]  (fp32)
// Also initializes phase-B exchange state each replay:
//   tagged mode: buf0 records = {h=0, tag=TAGB+1}; buf1 tags invalidated
//   fallback   : zero the 256 legacy flags
// ---------------------------------------------------------------------------
__global__ __launch_bounds__(256) void gates_x_mfma(
    const float* __restrict__ emb, const float* __restrict__ Wih,
    const float* __restrict__ bih, const float* __restrict__ bhh,
    const int* __restrict__ seq, float* __restrict__ gx,
    u64* b0, u64* b1, unsigned int* flags, int tagged)
{
    if (tagged && blockIdx.y == 0) {
        const int gid = blockIdx.x * 256 + threadIdx.x;   // 0..131071
        if (gid < NREC)          b0[gid] = ((u64)(TAGB + 1u)) << 32;   // h0=0, tag=1
        else if (gid < 2 * NREC) b1[gid - NREC] = 0ull;                // invalid tag
    }
    if (blockIdx.y == 1 && blockIdx.x == 0) flags[threadIdx.x] = 0u;

    __shared__ unsigned short Als[64 * 136];   // 64 rows x 128 k bf16, stride 136
    __shared__ int tok[64];

    const int tid = threadIdx.x;
    const int s   = blockIdx.x;
    const int r0  = blockIdx.y * 128;

    if (tid < 64) tok[tid] = seq[tid * SEQ + s];
    __syncthreads();

    const int w   = tid >> 6;
    const int l   = tid & 63;
    const int l16 = l & 15;
    const int kq  = l >> 4;

    const float* wrow0 = Wih + (size_t)(r0 + 32 * w + l16) * EMBED;
    const float* wrow1 = wrow0 + 16 * EMBED;

    floatx4 acc[4][2];
#pragma unroll
    for (int mt = 0; mt < 4; ++mt)
#pragma unroll
        for (int nt = 0; nt < 2; ++nt)
            acc[mt][nt] = (floatx4){0.f, 0.f, 0.f, 0.f};

    const int arow  = tid >> 2;
    const int apart = tid & 3;
    const float* asrc_base = emb + (size_t)tok[arow] * EMBED + apart * 32;
    unsigned short* adst = Als + arow * 136 + apart * 32;

    for (int kb = 0; kb < EMBED; kb += 128) {
        const float* asrc = asrc_base + kb;
#pragma unroll
        for (int j = 0; j < 4; ++j)
            *(bf16x8*)(adst + j * 8) = cvt8(asrc + j * 8);
        __syncthreads();

#pragma unroll
        for (int kc = 0; kc < 4; ++kc) {
            const int ko = kb + kc * 32 + kq * 8;
            const bf16x8 b0f = cvt8(wrow0 + ko);
            const bf16x8 b1f = cvt8(wrow1 + ko);
#pragma unroll
            for (int mt = 0; mt < 4; ++mt) {
                const bf16x8 af = *(const bf16x8*)(Als + (mt * 16 + l16) * 136 + kc * 32 + kq * 8);
                acc[mt][0] = __builtin_amdgcn_mfma_f32_16x16x32_bf16(af, b0f, acc[mt][0], 0, 0, 0);
                acc[mt][1] = __builtin_amdgcn_mfma_f32_16x16x32_bf16(af, b1f, acc[mt][1], 0, 0, 0);
            }
        }
        __syncthreads();
    }

    const int rA = r0 + 32 * w + l16;
    const float bv0 = bih[rA] + bhh[rA];
    const float bv1 = bih[rA + 16] + bhh[rA + 16];
    float* gxs = gx + (size_t)s * (R4 * BATCH);
#pragma unroll
    for (int nt = 0; nt < 2; ++nt) {
        const float bv = nt ? bv1 : bv0;
        const int r = rA + 16 * nt;
#pragma unroll
        for (int mt = 0; mt < 4; ++mt) {
            float4 v;
            v.x = acc[mt][nt][0] + bv;
            v.y = acc[mt][nt][1] + bv;
            v.z = acc[mt][nt][2] + bv;
            v.w = acc[mt][nt][3] + bv;
            *(float4*)(gxs + (size_t)r * BATCH + mt * 16 + kq * 4) = v;
        }
    }
}

// ---------------------------------------------------------------------------
// Phase B (tagged): 64 blocks x 512 thr (8 waves). NO barrier, NO flags, NO
// fences. h exchanged as 8-B tagged records {2 bf16, epoch} via relaxed
// agent atomics (MALL-coherent). Consumers spin directly on the records.
// Safety: the writer of tag t+2 into a record has consumed all t+1 records,
// whose producers consumed all tag-t records -> no overwrite before read.
// W_hh fragments resident in registers (launch_bounds(512,2) -> 256 VGPR).
// Wave w: gate mi=w&3, batch-half ng=w>>2 (2 n-tiles, 64 MFMAs/step).
// ---------------------------------------------------------------------------
__global__ __launch_bounds__(512, 2) void lstm_tagged(
    const float* __restrict__ gx, const float* __restrict__ Whh,
    u64* __restrict__ b0, u64* __restrict__ b1, float* __restrict__ out)
{
    __shared__ __align__(16) unsigned short smem[64 * 1032];   // 132,096 B
    unsigned short* hls = smem;                   // h image [b][1032] bf16
    float*          Slds = (float*)smem;          // 64x66 fp32, bytes 0..16895
    unsigned short* Hst  = smem + 8448;           // [b][16] bf16, bytes 16896..18943
    float*          Ost  = (float*)(smem + 9472); // [b][16] fp32, bytes 18944..23039

    const int tid = threadIdx.x;      // 0..511
    const int w   = tid >> 6;         // 0..7
    const int l   = tid & 63;
    const int l16 = l & 15;
    const int kq  = l >> 4;
    const int mi  = w & 3;            // gate
    const int ng  = w >> 2;           // batch half (0/1)
    const int u0  = blockIdx.x * UPB;

    // W_hh fragments -> registers (once). A row m=l16 -> unit u0+l16, gate mi.
    bf16x8 wfrag[32];
    {
        const float* wsrc = Whh + (size_t)(mi * HID + u0 + l16) * HID + kq * 8;
#pragma unroll
        for (int kc = 0; kc < 32; ++kc)
            wfrag[kc] = cvt8(wsrc + kc * 32);
    }

    // elementwise identity: thread owns (unit u0+ul) x batches {bb, bb+32}
    const int ul = tid >> 5;          // 0..15
    const int bb = tid & 31;          // 0..31
    const int u  = u0 + ul;

    float c0 = 0.f, c1 = 0.f, h0v = 0.f, h1v = 0.f;

    // gx(0)
    float gxr[8];
#pragma unroll
    for (int g = 0; g < 4; ++g) {
        gxr[g]     = gx[(size_t)(g * HID + u) * BATCH + bb];
        gxr[g + 4] = gx[(size_t)(g * HID + u) * BATCH + bb + 32];
    }

    for (int s = 0; s < SEQ; ++s) {
        const u64* hq = (s & 1) ? b1 : b0;
        u64*       hw = (s & 1) ? b0 : b1;
        const unsigned int rdtag = TAGB + (unsigned)(s + 1);
        const unsigned int wrtag = TAGB + (unsigned)(s + 2);

        // ---- stage: spin on tagged records, 2 batches of 32 ----------------
        // record r = B*512 + P : batch B, unit-pair P. Thread t covers P=t.
#pragma unroll
        for (int m = 0; m < 2; ++m) {
            u64 rec[32];
#pragma unroll
            for (int j = 0; j < 32; ++j)
                rec[j] = __hip_atomic_load(hq + (size_t)(m * 32 + j) * 512 + tid,
                                           __ATOMIC_RELAXED, __HIP_MEMORY_SCOPE_AGENT);
            for (;;) {
                unsigned int stale = 0u;
#pragma unroll
                for (int j = 0; j < 32; ++j)
                    if ((unsigned)(rec[j] >> 32) != rdtag) stale |= (1u << j);
                if (!__any(stale != 0u)) break;
#pragma unroll
                for (int j = 0; j < 32; ++j)
                    if (stale & (1u << j))
                        rec[j] = __hip_atomic_load(hq + (size_t)(m * 32 + j) * 512 + tid,
                                                   __ATOMIC_RELAXED, __HIP_MEMORY_SCOPE_AGENT);
            }
#pragma unroll
            for (int j = 0; j < 32; ++j)
                *(unsigned int*)((char*)smem + (size_t)(m * 32 + j) * 2064 + tid * 4)
                    = (unsigned int)rec[j];
        }
        __syncthreads();

        // ---- MFMA: A = wfrag (regs), B = h from LDS, 2 n-tiles -------------
        const unsigned short* hb0 = hls + (ng * 32 + l16) * 1032 + kq * 8;
        const unsigned short* hb1 = hb0 + 16 * 1032;
        floatx4 aA0 = (floatx4){0.f,0.f,0.f,0.f}, aA1 = (floatx4){0.f,0.f,0.f,0.f};
        floatx4 aB0 = (floatx4){0.f,0.f,0.f,0.f}, aB1 = (floatx4){0.f,0.f,0.f,0.f};
#pragma unroll
        for (int kc = 0; kc < 32; kc += 2) {
            const bf16x8 q00 = *(const bf16x8*)(hb0 + kc * 32);
            const bf16x8 q01 = *(const bf16x8*)(hb0 + (kc + 1) * 32);
            const bf16x8 q10 = *(const bf16x8*)(hb1 + kc * 32);
            const bf16x8 q11 = *(const bf16x8*)(hb1 + (kc + 1) * 32);
            aA0 = __builtin_amdgcn_mfma_f32_16x16x32_bf16(wfrag[kc],     q00, aA0, 0, 0, 0);
            aA1 = __builtin_amdgcn_mfma_f32_16x16x32_bf16(wfrag[kc + 1], q01, aA1, 0, 0, 0);
            aB0 = __builtin_amdgcn_mfma_f32_16x16x32_bf16(wfrag[kc],     q10, aB0, 0, 0, 0);
            aB1 = __builtin_amdgcn_mfma_f32_16x16x32_bf16(wfrag[kc + 1], q11, aB1, 0, 0, 0);
        }
        const floatx4 accA = aA0 + aA1;
        const floatx4 accB = aB0 + aB1;
        __syncthreads();   // all waves done reading hls -> safe to alias

        // D: row = mi*16 + kq*4 + r (gate*16+unit_local), col = batch
#pragma unroll
        for (int r = 0; r < 4; ++r) {
            Slds[(mi * 16 + kq * 4 + r) * 66 + ng * 32 + l16]      = accA[r];
            Slds[(mi * 16 + kq * 4 + r) * 66 + ng * 32 + 16 + l16] = accB[r];
        }
        __syncthreads();

        // ---- elementwise: 2 batches per thread -----------------------------
        {
            const float pi = Slds[(0 * 16 + ul) * 66 + bb] + gxr[0];
            const float pf = Slds[(1 * 16 + ul) * 66 + bb] + gxr[1];
            const float pg = Slds[(2 * 16 + ul) * 66 + bb] + gxr[2];
            const float po = Slds[(3 * 16 + ul) * 66 + bb] + gxr[3];
            const float ig = 1.f / (1.f + __expf(-pi));
            const float fg = 1.f / (1.f + __expf(-pf));
            const float gg = 2.f / (1.f + __expf(-2.f * pg)) - 1.f;
            const float og = 1.f / (1.f + __expf(-po));
            c0 = fg * c0 + ig * gg;
            h0v = og * (2.f / (1.f + __expf(-2.f * c0)) - 1.f);
        }
        {
            const float pi = Slds[(0 * 16 + ul) * 66 + bb + 32] + gxr[4];
            const float pf = Slds[(1 * 16 + ul) * 66 + bb + 32] + gxr[5];
            const float pg = Slds[(2 * 16 + ul) * 66 + bb + 32] + gxr[6];
            const float po = Slds[(3 * 16 + ul) * 66 + bb + 32] + gxr[7];
            const float ig = 1.f / (1.f + __expf(-pi));
            const float fg = 1.f / (1.f + __expf(-pf));
            const float gg = 2.f / (1.f + __expf(-2.f * pg)) - 1.f;
            const float og = 1.f / (1.f + __expf(-po));
            c1 = fg * c1 + ig * gg;
            h1v = og * (2.f / (1.f + __expf(-2.f * c1)) - 1.f);
        }
        Hst[bb * 16 + ul]        = f2bf(h0v);
        Hst[(bb + 32) * 16 + ul] = f2bf(h1v);
        Ost[bb * 16 + ul]        = h0v;
        Ost[(bb + 32) * 16 + ul] = h1v;
        __syncthreads();

        // prefetch next step's gx (in flight across pack + next spin)
        {
            const int sn = (s + 1 < SEQ) ? s + 1 : s;
            const float* gxs = gx + (size_t)sn * (R4 * BATCH);
#pragma unroll
            for (int g = 0; g < 4; ++g) {
                gxr[g]     = gxs[(size_t)(g * HID + u) * BATCH + bb];
                gxr[g + 4] = gxs[(size_t)(g * HID + u) * BATCH + bb + 32];
            }
        }

        // ---- pack + fire-and-forget tagged stores; coalesced out stores ----
        {
            const int pb = tid >> 3;        // batch 0..63
            const int pl = tid & 7;         // pair-local 0..7
            const unsigned short v0 = Hst[pb * 16 + 2 * pl];
            const unsigned short v1 = Hst[pb * 16 + 2 * pl + 1];
            const u64 recv = ((u64)wrtag << 32) | ((u64)v1 << 16) | (u64)v0;
            __hip_atomic_store(hw + (size_t)pb * 512 + (size_t)(u0 >> 1) + pl, recv,
                               __ATOMIC_RELAXED, __HIP_MEMORY_SCOPE_AGENT);
            uintx2 ov;
            ov.x = __float_as_uint(Ost[pb * 16 + 2 * pl]);
            ov.y = __float_as_uint(Ost[pb * 16 + 2 * pl + 1]);
            *(uintx2*)(out + ((size_t)pb * SEQ + s) * HID + u0 + 2 * pl) = ov;
        }
        // raw barrier (no vmcnt drain): each thread consumed its Hst/Ost
        // reads before arriving; stores/gx stay in flight.
        __builtin_amdgcn_s_barrier();
        asm volatile("" ::: "memory");
    }

    float* hlast = out + (size_t)BATCH * SEQ * HID;
    float* clast = hlast + (size_t)BATCH * HID;
    hlast[(size_t)bb * HID + u] = h0v;
    clast[(size_t)bb * HID + u] = c0;
    hlast[(size_t)(bb + 32) * HID + u] = h1v;
    clast[(size_t)(bb + 32) * HID + u] = c1;
}

// ---------------------------------------------------------------------------
// Phase B (fallback, proven round-6): 64 blocks x 1024 thr, flag barrier.
// Used only if ws lacks space for the tagged buffers.
// ---------------------------------------------------------------------------
__global__ __launch_bounds__(1024) void lstm_mfma(
    const float* __restrict__ gx, const float* __restrict__ Whh,
    unsigned short* __restrict__ h0buf, unsigned short* __restrict__ h1buf,
    unsigned int* flags, float* __restrict__ out)
{
    __shared__ __align__(16) unsigned short smem[64 * 1032];
    unsigned short* hls = smem;
    float*          Slds = (float*)smem;
    unsigned short* Hst  = smem + (16896 / 2);
    float*          Ost  = (float*)(smem + (18944 / 2));

    const int tid = threadIdx.x;
    const int w   = tid >> 6;
    const int l   = tid & 63;
    const int l16 = l & 15;
    const int kq  = l >> 4;
    const int mi  = w & 3;
    const int ni  = w >> 2;
    const int u0  = blockIdx.x * UPB;

    bf16x8 wfrag[32];
    {
        const float* src = Whh + (size_t)(mi * HID + u0 + l16) * HID + kq * 8;
#pragma unroll
        for (int kc = 0; kc < 32; ++kc)
            wfrag[kc] = cvt8(src + kc * 32);
    }

    const int ul = w & 15;
    const int b  = l;
    const int u  = u0 + ul;

    float c = 0.f, hval = 0.f;

    {
        u64* h0q = (u64*)h0buf;
#pragma unroll
        for (int j = 0; j < 16; ++j)
            __hip_atomic_store(h0q + j * 1024 + tid, 0ull,
                               __ATOMIC_RELAXED, __HIP_MEMORY_SCOPE_AGENT);
        asm volatile("s_waitcnt vmcnt(0)" ::: "memory");
    }
    __syncthreads();
    if (tid == 0)
        __hip_atomic_store(&flags[blockIdx.x], 1u, __ATOMIC_RELAXED,
                           __HIP_MEMORY_SCOPE_AGENT);

    float gxi = gx[(size_t)(0 * HID + u) * BATCH + b];
    float gxf = gx[(size_t)(1 * HID + u) * BATCH + b];
    float gxg = gx[(size_t)(2 * HID + u) * BATCH + b];
    float gxo = gx[(size_t)(3 * HID + u) * BATCH + b];

    if (w == 0) {
        for (;;) {
            unsigned int f = __hip_atomic_load(&flags[l], __ATOMIC_RELAXED,
                                               __HIP_MEMORY_SCOPE_AGENT);
            if (__all(f >= 1u)) break;
            __builtin_amdgcn_s_sleep(1);
        }
    }
    __syncthreads();
    asm volatile("" ::: "memory");

    for (int s = 0; s < SEQ; ++s) {
        const unsigned short* hb = (s & 1) ? h1buf : h0buf;
        unsigned short*       hn = (s & 1) ? h0buf : h1buf;

        {
            const u64* hq = (const u64*)hb;
            u64 tmp[16];
#pragma unroll
            for (int j = 0; j < 16; ++j)
                tmp[j] = __hip_atomic_load(hq + j * 1024 + tid,
                                           __ATOMIC_RELAXED, __HIP_MEMORY_SCOPE_AGENT);
#pragma unroll
            for (int j = 0; j < 16; ++j) {
                const int cc = j * 1024 + tid;
                *(u64*)(hls + (cc >> 8) * 1032 + (cc & 255) * 4) = tmp[j];
            }
        }
        __syncthreads();

        const unsigned short* hbase = hls + (ni * 16 + l16) * 1032 + kq * 8;
        floatx4 acc0 = (floatx4){0.f, 0.f, 0.f, 0.f};
        floatx4 acc1 = (floatx4){0.f, 0.f, 0.f, 0.f};
#pragma unroll
        for (int kc = 0; kc < 32; kc += 2) {
            const bf16x8 bf0 = *(const bf16x8*)(hbase + kc * 32);
            const bf16x8 bf1 = *(const bf16x8*)(hbase + (kc + 1) * 32);
            acc0 = __builtin_amdgcn_mfma_f32_16x16x32_bf16(wfrag[kc],     bf0, acc0, 0, 0, 0);
            acc1 = __builtin_amdgcn_mfma_f32_16x16x32_bf16(wfrag[kc + 1], bf1, acc1, 0, 0, 0);
        }
        const floatx4 acc = acc0 + acc1;
        __syncthreads();

#pragma unroll
        for (int r = 0; r < 4; ++r)
            Slds[(mi * 16 + kq * 4 + r) * 66 + ni * 16 + l16] = acc[r];
        __syncthreads();

        const float pi = Slds[(0 * 16 + ul) * 66 + b] + gxi;
        const float pf = Slds[(1 * 16 + ul) * 66 + b] + gxf;
        const float pg = Slds[(2 * 16 + ul) * 66 + b] + gxg;
        const float po = Slds[(3 * 16 + ul) * 66 + b] + gxo;

        const float ig = 1.f / (1.f + __expf(-pi));
        const float fg = 1.f / (1.f + __expf(-pf));
        const float gg = 2.f / (1.f + __expf(-2.f * pg)) - 1.f;
        const float og = 1.f / (1.f + __expf(-po));
        c = fg * c + ig * gg;
        const float th = 2.f / (1.f + __expf(-2.f * c)) - 1.f;
        hval = og * th;

        Hst[b * UPB + ul] = f2bf(hval);
        Ost[b * UPB + ul] = hval;
        __syncthreads();

        if (w < 4) {
            const int bb = tid >> 2, part = tid & 3;
            union { uintx2 v; u64 q; } hv;
            hv.v = *(const uintx2*)(Hst + bb * UPB + part * 4);
            const floatx4 ov = *(const floatx4*)(Ost + bb * UPB + part * 4);
            *(floatx4*)(out + ((size_t)bb * SEQ + s) * HID + u0 + part * 4) = ov;
            __hip_atomic_store((u64*)(hn + (size_t)bb * HID + u0 + part * 4), hv.q,
                               __ATOMIC_RELAXED, __HIP_MEMORY_SCOPE_AGENT);
            asm volatile("s_waitcnt vmcnt(0)" ::: "memory");
        }
        __syncthreads();
        const unsigned int ep = (unsigned int)(s + 2);
        if (tid == 0)
            __hip_atomic_store(&flags[blockIdx.x], ep, __ATOMIC_RELAXED,
                               __HIP_MEMORY_SCOPE_AGENT);

        {
            const int sn = (s + 1 < SEQ) ? s + 1 : s;
            const float* gxs = gx + (size_t)sn * (R4 * BATCH);
            gxi = gxs[(size_t)(0 * HID + u) * BATCH + b];
            gxf = gxs[(size_t)(1 * HID + u) * BATCH + b];
            gxg = gxs[(size_t)(2 * HID + u) * BATCH + b];
            gxo = gxs[(size_t)(3 * HID + u) * BATCH + b];
        }

        if (w == 0) {
            for (;;) {
                unsigned int f = __hip_atomic_load(&flags[l], __ATOMIC_RELAXED,
                                                   __HIP_MEMORY_SCOPE_AGENT);
                if (__all(f >= ep)) break;
                __builtin_amdgcn_s_sleep(1);
            }
        }
        __syncthreads();
        asm volatile("" ::: "memory");
    }

    float* hlast = out + (size_t)BATCH * SEQ * HID;
    float* clast = hlast + (size_t)BATCH * HID;
    hlast[(size_t)b * HID + u] = hval;
    clast[(size_t)b * HID + u] = c;
}

// ---------------------------------------------------------------------------
extern "C" void kernel_launch(void* const* d_in, const int* in_sizes, int n_in,
                              void* d_out, int out_size, void* d_ws, size_t ws_size,
                              hipStream_t stream)
{
    const float* emb = (const float*)d_in[0];
    const float* Wih = (const float*)d_in[1];
    const float* Whh = (const float*)d_in[2];
    const float* bih = (const float*)d_in[3];
    const float* bhh = (const float*)d_in[4];
    const int*   seq = (const int*)d_in[5];
    float* out = (float*)d_out;

    const size_t gxBytes = (size_t)SEQ * R4 * BATCH * 4;
    float* gx = (float*)d_ws;

    // tagged layout: gx + buf0(256KB) + buf1(256KB)
    u64* b0 = (u64*)((char*)d_ws + gxBytes);
    u64* b1 = b0 + NREC;
    const size_t need_tag = gxBytes + (size_t)2 * NREC * 8;
    const int tagged = (ws_size >= need_tag) ? 1 : 0;

    // fallback layout: gx + h0/h1 (u16) + flags
    unsigned short* h0 = (unsigned short*)((char*)d_ws + gxBytes);
    unsigned short* h1 = h0 + (size_t)BATCH * HID;
    const size_t need_flag = gxBytes + (size_t)2 * BATCH * HID * 2 + NBLK * 4;
    unsigned int* flags;
    if (tagged) {
        flags = (unsigned int*)(b1 + NREC);          // unused, scratch past bufs?
        if (ws_size < need_tag + NBLK * 4)
            flags = (unsigned int*)((float*)d_out + (size_t)BATCH * SEQ * HID
                                    + 2 * (size_t)BATCH * HID - NBLK);
    } else if (ws_size >= need_flag) {
        flags = (unsigned int*)(h1 + (size_t)BATCH * HID);
    } else {
        flags = (unsigned int*)((float*)d_out + (size_t)BATCH * SEQ * HID
                                + 2 * (size_t)BATCH * HID - NBLK);
    }

    dim3 gA(512, 32);
    gates_x_mfma<<<gA, 256, 0, stream>>>(emb, Wih, bih, bhh, seq, gx,
                                         b0, b1, flags, tagged);

    if (tagged) {
        lstm_tagged<<<dim3(PBLK), dim3(512), 0, stream>>>(gx, Whh, b0, b1, out);
    } else {
        void* args[] = { (void*)&gx, (void*)&Whh, (void*)&h0, (void*)&h1,
                         (void*)&flags, (void*)&out };
        hipError_t lerr = hipLaunchCooperativeKernel((void*)lstm_mfma, dim3(PBLK),
                                                     dim3(1024), args, 0, stream);
        if (lerr != hipSuccess)
            lstm_mfma<<<dim3(PBLK), dim3(1024), 0, stream>>>(gx, Whh, h0, h1, flags, out);
    }
}

// Round 8
// 6498.691 us; speedup vs baseline: 1.3961x; 1.3961x over previous
//
#include <hip/hip_runtime.h>

#define VOCAB 32000
#define EMBED 1024
#define HID   1024
#define BATCH 64
#define SEQ   512
#define R4    4096   // 4*HID gate rows, packed unit-major: row = 4*unit + gate
#define PBLK  64     // phase-B grid size
#define UPB   16     // units per phase-B block

typedef float floatx4 __attribute__((ext_vector_type(4)));
typedef unsigned int uintx2 __attribute__((ext_vector_type(2)));
typedef unsigned int uintx4 __attribute__((ext_vector_type(4)));
typedef short bf16x8  __attribute__((ext_vector_type(8)));   // 8 bf16 = 4 VGPRs
typedef unsigned long long u64;

// fp32 -> bf16 round-to-nearest-even
static __device__ __forceinline__ unsigned short f2bf(float x) {
    unsigned int u = __float_as_uint(x);
    u = (u + 0x7FFFu + ((u >> 16) & 1u)) >> 16;
    return (unsigned short)u;
}

// load 8 contiguous fp32, convert to bf16x8 fragment
static __device__ __forceinline__ bf16x8 cvt8(const float* p) {
    float4 a = ((const float4*)p)[0];
    float4 b = ((const float4*)p)[1];
    bf16x8 r;
    r[0] = (short)f2bf(a.x); r[1] = (short)f2bf(a.y);
    r[2] = (short)f2bf(a.z); r[3] = (short)f2bf(a.w);
    r[4] = (short)f2bf(b.x); r[5] = (short)f2bf(b.y);
    r[6] = (short)f2bf(b.z); r[7] = (short)f2bf(b.w);
    return r;
}

// 16-B system-scope (MALL-coherent) load/store: bypass L1+L2, serve at the
// device coherence point. Flag-gated data needs no atomicity, only bypass.
static __device__ __forceinline__ void sysld16(uintx4& d, const void* a) {
    asm volatile("global_load_dwordx4 %0, %1, off sc0 sc1"
                 : "=&v"(d) : "v"(a));
}
static __device__ __forceinline__ void sysst16(void* a, uintx4 d) {
    asm volatile("global_store_dwordx4 %0, %1, off sc0 sc1"
                 :: "v"(a), "v"(d) : "memory");
}

// ---------------------------------------------------------------------------
// Phase A: gx[s][r][b] with PACKED rows r = 4*unit + gate. Source W_ih row /
// bias for packed row r is (r&3)*HID + (r>>2). Same GEMM/tiling as before.
// Init blocks also zero phase-B h0 (128 KB) and set the 64 flags to 1.
// ---------------------------------------------------------------------------
__global__ __launch_bounds__(256) void gates_x_mfma(
    const float* __restrict__ emb, const float* __restrict__ Wih,
    const float* __restrict__ bih, const float* __restrict__ bhh,
    const int* __restrict__ seq, float* __restrict__ gx,
    unsigned int* h0z, unsigned int* flags)
{
    if (blockIdx.y == 0 && blockIdx.x < 128)
        h0z[blockIdx.x * 256 + threadIdx.x] = 0u;            // 128 KB zeros
    if (blockIdx.y == 1 && blockIdx.x == 0 && threadIdx.x < PBLK)
        flags[threadIdx.x] = 1u;                              // epoch 1 = h(0) ready

    __shared__ unsigned short Als[64 * 136];   // 64 rows x 128 k bf16, stride 136
    __shared__ int tok[64];

    const int tid = threadIdx.x;
    const int s   = blockIdx.x;
    const int r0  = blockIdx.y * 128;

    if (tid < 64) tok[tid] = seq[tid * SEQ + s];
    __syncthreads();

    const int w   = tid >> 6;
    const int l   = tid & 63;
    const int l16 = l & 15;
    const int kq  = l >> 4;

    const int rA  = r0 + 32 * w + l16;        // packed row
    const int sr0 = (rA & 3) * HID + (rA >> 2);
    const int rB  = rA + 16;
    const int sr1 = (rB & 3) * HID + (rB >> 2);
    const float* wrow0 = Wih + (size_t)sr0 * EMBED;
    const float* wrow1 = Wih + (size_t)sr1 * EMBED;

    floatx4 acc[4][2];
#pragma unroll
    for (int mt = 0; mt < 4; ++mt)
#pragma unroll
        for (int nt = 0; nt < 2; ++nt)
            acc[mt][nt] = (floatx4){0.f, 0.f, 0.f, 0.f};

    const int arow  = tid >> 2;
    const int apart = tid & 3;
    const float* asrc_base = emb + (size_t)tok[arow] * EMBED + apart * 32;
    unsigned short* adst = Als + arow * 136 + apart * 32;

    for (int kb = 0; kb < EMBED; kb += 128) {
        const float* asrc = asrc_base + kb;
#pragma unroll
        for (int j = 0; j < 4; ++j)
            *(bf16x8*)(adst + j * 8) = cvt8(asrc + j * 8);
        __syncthreads();

#pragma unroll
        for (int kc = 0; kc < 4; ++kc) {
            const int ko = kb + kc * 32 + kq * 8;
            const bf16x8 bw0 = cvt8(wrow0 + ko);
            const bf16x8 bw1 = cvt8(wrow1 + ko);
#pragma unroll
            for (int mt = 0; mt < 4; ++mt) {
                const bf16x8 af = *(const bf16x8*)(Als + (mt * 16 + l16) * 136 + kc * 32 + kq * 8);
                acc[mt][0] = __builtin_amdgcn_mfma_f32_16x16x32_bf16(af, bw0, acc[mt][0], 0, 0, 0);
                acc[mt][1] = __builtin_amdgcn_mfma_f32_16x16x32_bf16(af, bw1, acc[mt][1], 0, 0, 0);
            }
        }
        __syncthreads();
    }

    const float bv0 = bih[sr0] + bhh[sr0];
    const float bv1 = bih[sr1] + bhh[sr1];
    float* gxs = gx + (size_t)s * (R4 * BATCH);
#pragma unroll
    for (int nt = 0; nt < 2; ++nt) {
        const float bv = nt ? bv1 : bv0;
        const int r = rA + 16 * nt;
#pragma unroll
        for (int mt = 0; mt < 4; ++mt) {
            float4 v;
            v.x = acc[mt][nt][0] + bv;
            v.y = acc[mt][nt][1] + bv;
            v.z = acc[mt][nt][2] + bv;
            v.w = acc[mt][nt][3] + bv;
            *(float4*)(gxs + (size_t)r * BATCH + mt * 16 + kq * 4) = v;
        }
    }
}

// ---------------------------------------------------------------------------
// Phase B: 64 blocks x 512 thr (8 waves: gate-tile mi=w&3, batch-half nh=w>>2).
// W_hh fragments pinned in registers via opaque asm (unrecomputable values).
// Unit-major packing => lane holds all 4 gates of one (unit,batch): in-lane
// elementwise, c in-register, no gate-exchange LDS. h exchange: flag-gated
// 16-B sc0sc1 (MALL-coherent) loads/stores; per-thread spin on own producer.
// ---------------------------------------------------------------------------
__global__ __launch_bounds__(512, 2) void lstm_sc(
    const float* __restrict__ gx, const float* __restrict__ Whh,
    unsigned short* __restrict__ h0buf, unsigned short* __restrict__ h1buf,
    unsigned int* __restrict__ flags, float* __restrict__ out)
{
    __shared__ __align__(16) unsigned short hls[64 * 1032];  // h image, 132 KB
    __shared__ __align__(16) unsigned short Hst[64 * 16];    // h out [b][u] bf16
    __shared__ __align__(16) float          Ost[64 * 16];    // h out [b][u] fp32

    const int tid = threadIdx.x;      // 0..511
    const int w   = tid >> 6;         // 0..7
    const int l   = tid & 63;
    const int l16 = l & 15;
    const int kq  = l >> 4;
    const int mi  = w & 3;            // m-tile (4 units x 4 gates)
    const int nh  = w >> 2;           // batch half
    const int u0  = blockIdx.x * UPB;

    // W_hh fragments -> registers, then pin (opaque redefinition: the loads
    // cannot be re-materialized inside the loop).
    bf16x8 wfrag[32];
    {
        const int plr  = 16 * mi + l16;           // packed local row
        const int gsrc = plr & 3;
        const int usrc = u0 + (plr >> 2);
        const float* wsrc = Whh + ((size_t)gsrc * HID + usrc) * HID + kq * 8;
#pragma unroll
        for (int kc = 0; kc < 32; ++kc)
            wfrag[kc] = cvt8(wsrc + kc * 32);
    }
#pragma unroll
    for (int kc = 0; kc < 32; ++kc)
        asm volatile("" : "+v"(wfrag[kc]));

    // lane identity: unit ul, batches b0 / b1 = b0+16
    const int ul = 4 * mi + (l >> 4);
    const int b0 = 32 * nh + (l & 15);
    const int b1 = b0 + 16;
    const int ug = u0 + ul;

    // stage identity: producer sp (cols 16sp..16sp+16), rows sub+8i
    const int sp  = tid >> 3;         // 0..63
    const int sub = tid & 7;

    float cA = 0.f, cB = 0.f, hA = 0.f, hB = 0.f;

    float gr[8];
#pragma unroll
    for (int g = 0; g < 4; ++g) {
        gr[g]     = gx[(size_t)(4 * ug + g) * BATCH + b0];
        gr[g + 4] = gx[(size_t)(4 * ug + g) * BATCH + b1];
    }

    for (int s = 0; s < SEQ; ++s) {
        const unsigned short* hb = (s & 1) ? h1buf : h0buf;
        unsigned short*       hn = (s & 1) ? h0buf : h1buf;

        // ---- per-thread spin on own producer, then 16x16-B MALL loads ------
        {
            const unsigned need = (unsigned)(s + 1);
            while (__hip_atomic_load(&flags[sp], __ATOMIC_RELAXED,
                                     __HIP_MEMORY_SCOPE_AGENT) < need)
                __builtin_amdgcn_s_sleep(1);

            const char* srcb = (const char*)hb + (size_t)sp * 32;
            uintx4 rv[16];
#pragma unroll
            for (int i = 0; i < 8; ++i) {
                const char* rp = srcb + (size_t)(sub + 8 * i) * 2048;
                sysld16(rv[2 * i],     rp);
                sysld16(rv[2 * i + 1], rp + 16);
            }
            asm volatile("s_waitcnt vmcnt(0)" ::: "memory");
            __builtin_amdgcn_sched_barrier(0);
#pragma unroll
            for (int i = 0; i < 8; ++i) {
                char* dp = (char*)hls + (size_t)(sub + 8 * i) * 2064 + sp * 32;
                *(uintx4*)dp        = rv[2 * i];
                *(uintx4*)(dp + 16) = rv[2 * i + 1];
            }
        }
        __syncthreads();                                   // hls ready

        // ---- MFMA: A = pinned W, B = h from LDS, 2 n-tiles -----------------
        const unsigned short* hp0 = hls + (size_t)(32 * nh + l16) * 1032 + kq * 8;
        const unsigned short* hp1 = hp0 + 16 * 1032;
        floatx4 a00 = (floatx4){0.f,0.f,0.f,0.f}, a01 = (floatx4){0.f,0.f,0.f,0.f};
        floatx4 a10 = (floatx4){0.f,0.f,0.f,0.f}, a11 = (floatx4){0.f,0.f,0.f,0.f};
#pragma unroll
        for (int kc = 0; kc < 32; kc += 2) {
            const bf16x8 q00 = *(const bf16x8*)(hp0 + kc * 32);
            const bf16x8 q01 = *(const bf16x8*)(hp0 + (kc + 1) * 32);
            const bf16x8 q10 = *(const bf16x8*)(hp1 + kc * 32);
            const bf16x8 q11 = *(const bf16x8*)(hp1 + (kc + 1) * 32);
            a00 = __builtin_amdgcn_mfma_f32_16x16x32_bf16(wfrag[kc],     q00, a00, 0, 0, 0);
            a01 = __builtin_amdgcn_mfma_f32_16x16x32_bf16(wfrag[kc + 1], q01, a01, 0, 0, 0);
            a10 = __builtin_amdgcn_mfma_f32_16x16x32_bf16(wfrag[kc],     q10, a10, 0, 0, 0);
            a11 = __builtin_amdgcn_mfma_f32_16x16x32_bf16(wfrag[kc + 1], q11, a11, 0, 0, 0);
        }
        const floatx4 accA = a00 + a01;   // gates i,f,g,o for (ug, b0)
        const floatx4 accB = a10 + a11;   // gates i,f,g,o for (ug, b1)

        // ---- in-lane elementwise (no gate exchange) ------------------------
        {
            const float pi = accA[0] + gr[0];
            const float pf = accA[1] + gr[1];
            const float pg = accA[2] + gr[2];
            const float po = accA[3] + gr[3];
            const float ig = 1.f / (1.f + __expf(-pi));
            const float fg = 1.f / (1.f + __expf(-pf));
            const float gg = 2.f / (1.f + __expf(-2.f * pg)) - 1.f;
            const float og = 1.f / (1.f + __expf(-po));
            cA = fg * cA + ig * gg;
            hA = og * (2.f / (1.f + __expf(-2.f * cA)) - 1.f);
        }
        {
            const float pi = accB[0] + gr[4];
            const float pf = accB[1] + gr[5];
            const float pg = accB[2] + gr[6];
            const float po = accB[3] + gr[7];
            const float ig = 1.f / (1.f + __expf(-pi));
            const float fg = 1.f / (1.f + __expf(-pf));
            const float gg = 2.f / (1.f + __expf(-2.f * pg)) - 1.f;
            const float og = 1.f / (1.f + __expf(-po));
            cB = fg * cB + ig * gg;
            hB = og * (2.f / (1.f + __expf(-2.f * cB)) - 1.f);
        }
        Hst[(size_t)b0 * 16 + ul] = f2bf(hA);
        Hst[(size_t)b1 * 16 + ul] = f2bf(hB);
        Ost[(size_t)b0 * 16 + ul] = hA;
        Ost[(size_t)b1 * 16 + ul] = hB;
        __syncthreads();                                   // Hst/Ost ready

        // ---- pack: coalesced out (plain) + h (16-B MALL stores) ------------
        if (tid < 256) {
            const int pb = tid >> 2, q = tid & 3;
            const floatx4 ov = *(const floatx4*)((const char*)Ost + (size_t)pb * 64 + q * 16);
            *(floatx4*)(out + ((size_t)pb * SEQ + s) * HID + u0 + q * 4) = ov;
        }
        if (tid < 128) {
            const int pb = tid >> 1, hh = tid & 1;
            const uintx4 hv = *(const uintx4*)((const char*)Hst + (size_t)pb * 32 + hh * 16);
            sysst16((char*)hn + (size_t)pb * 2048 + u0 * 2 + hh * 16, hv);
            asm volatile("s_waitcnt vmcnt(0)" ::: "memory");
        }
        __syncthreads();                                   // h acked at MALL
        if (tid == 0)
            __hip_atomic_store(&flags[blockIdx.x], (unsigned)(s + 2),
                               __ATOMIC_RELAXED, __HIP_MEMORY_SCOPE_AGENT);

        // prefetch next step's gx (in flight across next spin)
        {
            const int sn = (s + 1 < SEQ) ? s + 1 : s;
            const float* gxs = gx + (size_t)sn * (R4 * BATCH);
#pragma unroll
            for (int g = 0; g < 4; ++g) {
                gr[g]     = gxs[(size_t)(4 * ug + g) * BATCH + b0];
                gr[g + 4] = gxs[(size_t)(4 * ug + g) * BATCH + b1];
            }
        }
    }

    // drain: all blocks past final pack (protects out-tail fallback layout)
    {
        const int p = tid & 63;
        while (__hip_atomic_load(&flags[p], __ATOMIC_RELAXED,
                                 __HIP_MEMORY_SCOPE_AGENT) < (unsigned)(SEQ + 1))
            __builtin_amdgcn_s_sleep(1);
    }
    __syncthreads();

    float* hlast = out + (size_t)BATCH * SEQ * HID;
    float* clast = hlast + (size_t)BATCH * HID;
    hlast[(size_t)b0 * HID + ug] = hA;  clast[(size_t)b0 * HID + ug] = cA;
    hlast[(size_t)b1 * HID + ug] = hB;  clast[(size_t)b1 * HID + ug] = cB;
}

// ---------------------------------------------------------------------------
extern "C" void kernel_launch(void* const* d_in, const int* in_sizes, int n_in,
                              void* d_out, int out_size, void* d_ws, size_t ws_size,
                              hipStream_t stream)
{
    const float* emb = (const float*)d_in[0];
    const float* Wih = (const float*)d_in[1];
    const float* Whh = (const float*)d_in[2];
    const float* bih = (const float*)d_in[3];
    const float* bhh = (const float*)d_in[4];
    const int*   seq = (const int*)d_in[5];
    float* out = (float*)d_out;

    const size_t gxBytes = (size_t)SEQ * R4 * BATCH * 4;
    const size_t hBytes  = (size_t)BATCH * HID * 2;          // 128 KB
    float* gx = (float*)d_ws;

    unsigned short *h0, *h1;
    unsigned int* flags;
    if (ws_size >= gxBytes + 2 * hBytes + PBLK * 4) {
        h0 = (unsigned short*)((char*)d_ws + gxBytes);
        h1 = h0 + (size_t)BATCH * HID;
        flags = (unsigned int*)((char*)h1 + hBytes);
    } else {
        // fallback: live in the out tail (h_last/c_last region, 512 KB).
        // Safe: phase B drains all blocks past the final pack before the
        // tail is overwritten with h_last/c_last.
        char* tail = (char*)d_out + (size_t)BATCH * SEQ * HID * 4;
        h0 = (unsigned short*)tail;
        h1 = h0 + (size_t)BATCH * HID;
        flags = (unsigned int*)(tail + 2 * hBytes);
    }

    dim3 gA(512, 32);
    gates_x_mfma<<<gA, 256, 0, stream>>>(emb, Wih, bih, bhh, seq, gx,
                                         (unsigned int*)h0, flags);
    lstm_sc<<<dim3(PBLK), dim3(512), 0, stream>>>(gx, Whh, h0, h1, flags, out);
}